// Round 11
// baseline (874.719 us; speedup 1.0000x reference)
//
#include <hip/hip_runtime.h>
#include <limits.h>
#include <math.h>

#define V_N 100000
#define C_N 420000
#define E_N 1260000
#define L_N 3
#define NCBLK 1641   // ceil(C_N/256)
#define NVBLK 391    // ceil(V_N/256)
#define NEBLK 4922   // ceil(E_N/256)

__device__ __forceinline__ float fsig(float x) {
    return 1.0f / (1.0f + __expf(-x));
}
__device__ __forceinline__ float ftanh(float x) {
    x = fminf(fmaxf(x, -15.0f), 15.0f);
    float t = __expf(2.0f * x);
    return (t - 1.0f) / (t + 1.0f);
}

// ---------------------------------------------------------------------------
// Consolidated per-(side,layer) weight block, stride 1040 floats:
//   [j*16 + 0..4]  = w1 row j (5)      [j*16 + 5] = b1[j]
//   [j*16 + 6..14] = wp[j][k] = sum_o wih[k][o]*W2[o][j]   [j*16+15] = pad
//   [1024 + k]     = c2[k] = sum_o wih[k][o]*b2[o]
// ---------------------------------------------------------------------------
__global__ void k_prep(const float* __restrict__ v2c_w1, const float* __restrict__ v2c_b1,
                       const float* __restrict__ v2c_w2, const float* __restrict__ v2c_b2,
                       const float* __restrict__ c2v_w1, const float* __restrict__ c2v_b1,
                       const float* __restrict__ c2v_w2, const float* __restrict__ c2v_b2,
                       const float* __restrict__ cls_wih, const float* __restrict__ var_wih,
                       float* __restrict__ prep) {
    int t = blockIdx.x * blockDim.x + threadIdx.x;
    if (t >= 6 * 1040) return;
    int s = t / 1040, r = t % 1040;
    int side = s / 3, l = s % 3;
    const float* w1  = (side ? c2v_w1 : v2c_w1) + l * 320;
    const float* b1  = (side ? c2v_b1 : v2c_b1) + l * 64;
    const float* W2  = (side ? c2v_w2 : v2c_w2) + l * 4096;
    const float* b2  = (side ? c2v_b2 : v2c_b2) + l * 64;
    const float* wih = (side ? var_wih : cls_wih) + l * 576;
    float v = 0.0f;
    if (r < 1024) {
        int j = r >> 4, q = r & 15;
        if (q < 5) v = w1[j * 5 + q];
        else if (q == 5) v = b1[j];
        else if (q < 15) {
            int k = q - 6; float a = 0.0f;
            for (int o = 0; o < 64; ++o) a += wih[k * 64 + o] * W2[o * 64 + j];
            v = a;
        }
    } else if (r < 1033) {
        int k = r - 1024; float a = 0.0f;
        for (int o = 0; o < 64; ++o) a += wih[k * 64 + o] * b2[o];
        v = a;
    }
    prep[t] = v;
}

// ---------------------------------------------------------------------------
// Histogram + rank in ONE atomic pass (rank = old count).
// ---------------------------------------------------------------------------
__global__ __launch_bounds__(256) void k_countrank(const int* __restrict__ ci,
                                                   const int* __restrict__ vi,
                                                   int* __restrict__ cntC, int* __restrict__ cntV,
                                                   int* __restrict__ rankC, int* __restrict__ rankV) {
    int e = blockIdx.x * 256 + threadIdx.x;
    if (e >= E_N) return;
    rankC[e] = atomicAdd(&cntC[ci[e]], 1);
    rankV[e] = atomicAdd(&cntV[vi[e]], 1);
}

// Dual-side block sums: blocks [0,nbC) -> C, [nbC,nbC+nbV) -> V.
__global__ __launch_bounds__(256) void k_scanA(const int* __restrict__ cntC,
                                               const int* __restrict__ cntV, int nbC,
                                               int* __restrict__ bsumC, int* __restrict__ bsumV) {
    int b = blockIdx.x, t = threadIdx.x;
    const int* cnt; int N; int* bs; int bb;
    if (b < nbC) { cnt = cntC; N = C_N; bs = bsumC; bb = b; }
    else         { cnt = cntV; N = V_N; bs = bsumV; bb = b - nbC; }
    int base = bb * 1024 + t * 4;
    int s = 0;
    #pragma unroll
    for (int q = 0; q < 4; ++q) { int i = base + q; if (i < N) s += cnt[i]; }
    __shared__ int sh[256];
    sh[t] = s; __syncthreads();
    for (int d = 128; d; d >>= 1) { if (t < d) sh[t] += sh[t + d]; __syncthreads(); }
    if (t == 0) bs[bb] = sh[0];
}

__global__ __launch_bounds__(512) void k_scanB(int* __restrict__ bsumC, int nbC, int* __restrict__ totC,
                                               int* __restrict__ bsumV, int nbV, int* __restrict__ totV) {
    int* bsum = blockIdx.x ? bsumV : bsumC;
    int nb    = blockIdx.x ? nbV : nbC;
    int* tot  = blockIdx.x ? totV : totC;
    __shared__ int sh[512];
    int t = threadIdx.x;
    int v = (t < nb) ? bsum[t] : 0;
    sh[t] = v; __syncthreads();
    for (int d = 1; d < 512; d <<= 1) {
        int add = (t >= d) ? sh[t - d] : 0;
        __syncthreads();
        sh[t] += add;
        __syncthreads();
    }
    if (t < nb) bsum[t] = sh[t] - v;
    if (t == nb - 1) *tot = sh[t];
}

__global__ __launch_bounds__(256) void k_scanC(const int* __restrict__ cntC,
                                               const int* __restrict__ cntV, int nbC,
                                               const int* __restrict__ bsumC,
                                               const int* __restrict__ bsumV,
                                               int* __restrict__ rowC, int* __restrict__ rowV) {
    int b = blockIdx.x, t = threadIdx.x;
    const int* cnt; int N; const int* bs; int* row; int bb;
    if (b < nbC) { cnt = cntC; N = C_N; bs = bsumC; row = rowC; bb = b; }
    else         { cnt = cntV; N = V_N; bs = bsumV; row = rowV; bb = b - nbC; }
    int base = bb * 1024 + t * 4;
    int v[4], local[4];
    #pragma unroll
    for (int q = 0; q < 4; ++q) { int i = base + q; v[q] = (i < N) ? cnt[i] : 0; }
    local[0] = 0; local[1] = v[0]; local[2] = v[0] + v[1]; local[3] = v[0] + v[1] + v[2];
    int mysum = local[3] + v[3];
    __shared__ int sh[256];
    sh[t] = mysum; __syncthreads();
    for (int d = 1; d < 256; d <<= 1) {
        int add = (t >= d) ? sh[t - d] : 0;
        __syncthreads();
        sh[t] += add;
        __syncthreads();
    }
    int excl = sh[t] - mysum + bs[bb];
    #pragma unroll
    for (int q = 0; q < 4; ++q) {
        int i = base + q;
        if (i < N) row[i] = excl + local[q];
    }
}

// ---------------------------------------------------------------------------
// One-time: permute edge data into both CSR orders.
//   edataC[p] = {var (gather), cls (segment), ef.x, ef.y}   (clause-sorted)
//   edataV[p] = {cls (gather), var (segment), ef.x, ef.y}   (var-sorted)
// ---------------------------------------------------------------------------
__global__ __launch_bounds__(256) void k_permute(const int* __restrict__ var_idx,
                                                 const int* __restrict__ cls_idx,
                                                 const int* __restrict__ rankC,
                                                 const int* __restrict__ rankV,
                                                 const float* __restrict__ ef,
                                                 const int* __restrict__ rowC,
                                                 const int* __restrict__ rowV,
                                                 int4* __restrict__ edataC,
                                                 int4* __restrict__ edataV) {
    int e = blockIdx.x * 256 + threadIdx.x;
    if (e >= E_N) return;
    int v = var_idx[e], c = cls_idx[e];
    float2 efv = *(const float2*)(ef + 2 * (size_t)e);
    int zx = __float_as_int(efv.x), zw = __float_as_int(efv.y);
    int4 dC; dC.x = v; dC.y = c; dC.z = zx; dC.w = zw;
    edataC[rowC[c] + rankC[e]] = dC;
    int4 dV; dV.x = c; dV.y = v; dV.z = zx; dV.w = zw;
    edataV[rowV[v] + rankV[e]] = dV;
}

// ---------------------------------------------------------------------------
// Layer-0 attention logits from cf0 + per-block max partials; zeroes Sg.
// ---------------------------------------------------------------------------
__global__ __launch_bounds__(256) void k_att0(const float* __restrict__ cf,
                                              const float* __restrict__ aw1,
                                              const float* __restrict__ ab1,
                                              const float* __restrict__ aw2,
                                              const float* __restrict__ ab2,
                                              float* __restrict__ logits,
                                              float* __restrict__ pmax,
                                              float* __restrict__ Sg) {
    if (blockIdx.x == 0 && threadIdx.x < 8) Sg[threadIdx.x] = 0.0f;
    int c = blockIdx.x * blockDim.x + threadIdx.x;
    float logit = -1e30f;
    if (c < C_N) {
        float h0 = cf[c * 3], h1 = cf[c * 3 + 1], h2 = cf[c * 3 + 2];
        float acc = ab2[0];
        #pragma unroll
        for (int k = 0; k < 64; ++k) {
            float tv = ftanh(aw1[k * 3] * h0 + aw1[k * 3 + 1] * h1 +
                             aw1[k * 3 + 2] * h2 + ab1[k]);
            acc += aw2[k] * tv;
        }
        logits[c] = acc;
        logit = acc;
    }
    float m = logit;
    #pragma unroll
    for (int off = 32; off; off >>= 1) m = fmaxf(m, __shfl_xor(m, off));
    __shared__ float smax[4];
    int lane = threadIdx.x & 63, wid = threadIdx.x >> 6;
    if (lane == 0) smax[wid] = m;
    __syncthreads();
    if (threadIdx.x == 0)
        pmax[blockIdx.x] = fmaxf(fmaxf(smax[0], smax[1]), fmaxf(smax[2], smax[3]));
}

// ---------------------------------------------------------------------------
// Edge kernel, destination-sorted: blocks [0,NEBLK) clause side (v2c msgs
// from vf), [NEBLK,2*NEBLK) var side (c2v msgs from cf).  Streams edata
// coalesced, computes message, segmented-reduces in LDS (edges of one node
// are contiguous), writes fp32 sums to gsum: interior segments plain store,
// boundary segments atomicAdd (gsum pre-zeroed).  First NCBLK clause blocks
// also fold this layer's softmax partial sum.
// ---------------------------------------------------------------------------
__global__ __launch_bounds__(256) void k_edge2(const float* __restrict__ vf,
                                               const float* __restrict__ cf,
                                               const int4* __restrict__ edataC,
                                               const int4* __restrict__ edataV,
                                               const float* __restrict__ prepA,
                                               const float* __restrict__ prepB,
                                               const float* __restrict__ logits,
                                               const float* __restrict__ pmax,
                                               float* __restrict__ SgL,
                                               float* __restrict__ gsumC,
                                               float* __restrict__ gsumV) {
    __shared__ float W[1040];
    __shared__ float lmsg[256 * 9];
    __shared__ int scid[256];
    __shared__ float sh4[4];
    const bool sideC = blockIdx.x < NEBLK;
    const int blk = sideC ? blockIdx.x : blockIdx.x - NEBLK;
    const int4* __restrict__ edata = sideC ? edataC : edataV;
    const float* __restrict__ feat = sideC ? vf : cf;
    const float* __restrict__ prepp = sideC ? prepA : prepB;
    float* __restrict__ gsum = sideC ? gsumC : gsumV;
    int t = threadIdx.x;
    for (int i = t; i < 1040; i += 256) W[i] = prepp[i];
    int p0 = blk * 256;
    int p = p0 + t;
    int myc = INT_MIN;
    float u[9];
    int4 ed;
    if (p < E_N) ed = edata[p];
    __syncthreads();   // W ready
    if (p < E_N) {
        myc = ed.y;
        float x0 = feat[ed.x * 3], x1 = feat[ed.x * 3 + 1], x2 = feat[ed.x * 3 + 2];
        float x3 = __int_as_float(ed.z), x4 = __int_as_float(ed.w);
        #pragma unroll
        for (int k = 0; k < 9; ++k) u[k] = 0.0f;
        for (int j = 0; j < 64; ++j) {
            const float* wj = &W[j * 16];
            float h = fmaxf(wj[0] * x0 + wj[1] * x1 + wj[2] * x2 +
                            wj[3] * x3 + wj[4] * x4 + wj[5], 0.0f);
            #pragma unroll
            for (int k = 0; k < 9; ++k) u[k] += wj[6 + k] * h;
        }
        #pragma unroll
        for (int k = 0; k < 9; ++k) lmsg[t * 9 + k] = u[k];
    }
    scid[t] = myc;
    __syncthreads();
    if (p < E_N) {
        bool head_any = (t == 0) || (scid[t - 1] != myc);
        if (head_any) {
            bool trueHead = true;
            if (t == 0 && p0 > 0)
                trueHead = (((const int*)edata)[(size_t)(p0 - 1) * 4 + 1] != myc);
            float acc[9];
            #pragma unroll
            for (int k = 0; k < 9; ++k) acc[k] = 0.0f;
            int j = t;
            while (j < 256 && scid[j] == myc) {
                #pragma unroll
                for (int k = 0; k < 9; ++k) acc[k] += lmsg[j * 9 + k];
                ++j;
            }
            bool ends = (j < 256);
            size_t base = (size_t)myc * 9;
            if (trueHead && ends) {
                #pragma unroll
                for (int k = 0; k < 9; ++k) gsum[base + k] = acc[k];
            } else {
                #pragma unroll
                for (int k = 0; k < 9; ++k) unsafeAtomicAdd(&gsum[base + k], acc[k]);
            }
        }
    }
    // -------- fused softmax partial (this layer's Sg), clause side only ----
    if (sideC && blk < NCBLK) {
        float m = -1e30f;
        for (int i = t; i < NCBLK; i += 256) m = fmaxf(m, pmax[i]);
        #pragma unroll
        for (int off = 32; off; off >>= 1) m = fmaxf(m, __shfl_xor(m, off));
        int lane = t & 63, wid = t >> 6;
        if (lane == 0) sh4[wid] = m;
        __syncthreads();
        float mm = fmaxf(fmaxf(sh4[0], sh4[1]), fmaxf(sh4[2], sh4[3]));
        __syncthreads();
        int c = blk * 256 + t;
        float ex = (c < C_N) ? __expf(logits[c] - mm) : 0.0f;
        #pragma unroll
        for (int off = 32; off; off >>= 1) ex += __shfl_xor(ex, off);
        if (lane == 0) sh4[wid] = ex;
        __syncthreads();
        if (t == 0) {
            unsafeAtomicAdd(&SgL[0], sh4[0] + sh4[1] + sh4[2] + sh4[3]);
            if (blk == 0) SgL[1] = mm;
        }
    }
}

// ---------------------------------------------------------------------------
// Node kernel: blocks [0,NCBLK) clauses (gsumC + att-scale + GRU + next-layer
// logits), blocks [NCBLK,..) vars (gsumV + GRU).  gsum reads coalesced.
// ---------------------------------------------------------------------------
__global__ __launch_bounds__(256) void k_nodeM(const float* __restrict__ gsumC,
                                               const float* __restrict__ gsumV,
                                               const int* __restrict__ rowC,
                                               const int* __restrict__ rowV,
                                               const float* __restrict__ cfin,
                                               const float* __restrict__ vfin,
                                               float* __restrict__ cfout,
                                               float* __restrict__ vfout,
                                               const float* __restrict__ SgL,
                                               float* __restrict__ logits,
                                               float* __restrict__ pmax,
                                               const float* __restrict__ c2C,
                                               const float* __restrict__ c2V,
                                               const float* __restrict__ cls_whh,
                                               const float* __restrict__ cls_bih,
                                               const float* __restrict__ cls_bhh,
                                               const float* __restrict__ var_whh,
                                               const float* __restrict__ var_bih,
                                               const float* __restrict__ var_bhh,
                                               const float* __restrict__ aw1,
                                               const float* __restrict__ ab1,
                                               const float* __restrict__ aw2,
                                               const float* __restrict__ ab2,
                                               int do_att) {
    int b = blockIdx.x;
    if (b < NCBLK) {
        int i = b * 256 + threadIdx.x;
        float logit = -1e30f;
        if (i < C_N) {
            float u[9];
            #pragma unroll
            for (int k = 0; k < 9; ++k) u[k] = gsumC[(size_t)i * 9 + k];
            float cnt = (float)(rowC[i + 1] - rowC[i]);
            float scale = __expf(logits[i] - SgL[1]) / SgL[0];
            float h0 = cfin[i * 3], h1 = cfin[i * 3 + 1], h2 = cfin[i * 3 + 2];
            float gi[9], gh[9];
            #pragma unroll
            for (int k = 0; k < 9; ++k) gi[k] = scale * (u[k] + cnt * c2C[k]) + cls_bih[k];
            #pragma unroll
            for (int k = 0; k < 9; ++k)
                gh[k] = cls_whh[k * 3] * h0 + cls_whh[k * 3 + 1] * h1 + cls_whh[k * 3 + 2] * h2 + cls_bhh[k];
            float r0 = fsig(gi[0] + gh[0]), r1 = fsig(gi[1] + gh[1]), r2 = fsig(gi[2] + gh[2]);
            float z0 = fsig(gi[3] + gh[3]), z1 = fsig(gi[4] + gh[4]), z2 = fsig(gi[5] + gh[5]);
            float n0 = ftanh(gi[6] + r0 * gh[6]);
            float n1 = ftanh(gi[7] + r1 * gh[7]);
            float n2 = ftanh(gi[8] + r2 * gh[8]);
            float o0 = (1.0f - z0) * n0 + z0 * h0;
            float o1 = (1.0f - z1) * n1 + z1 * h1;
            float o2 = (1.0f - z2) * n2 + z2 * h2;
            cfout[i * 3 + 0] = o0;
            cfout[i * 3 + 1] = o1;
            cfout[i * 3 + 2] = o2;
            if (do_att) {
                float acc = ab2[0];
                #pragma unroll
                for (int k = 0; k < 64; ++k) {
                    float tv = ftanh(aw1[k * 3] * o0 + aw1[k * 3 + 1] * o1 +
                                     aw1[k * 3 + 2] * o2 + ab1[k]);
                    acc += aw2[k] * tv;
                }
                logits[i] = acc;
                logit = acc;
            }
        }
        if (do_att) {
            float m = logit;
            #pragma unroll
            for (int off = 32; off; off >>= 1) m = fmaxf(m, __shfl_xor(m, off));
            __shared__ float smax[4];
            int lane = threadIdx.x & 63, wid = threadIdx.x >> 6;
            if (lane == 0) smax[wid] = m;
            __syncthreads();
            if (threadIdx.x == 0)
                pmax[b] = fmaxf(fmaxf(smax[0], smax[1]), fmaxf(smax[2], smax[3]));
        }
    } else {
        int i = (b - NCBLK) * 256 + threadIdx.x;
        if (i >= V_N) return;
        float u[9];
        #pragma unroll
        for (int k = 0; k < 9; ++k) u[k] = gsumV[(size_t)i * 9 + k];
        float cnt = (float)(rowV[i + 1] - rowV[i]);
        float h0 = vfin[i * 3], h1 = vfin[i * 3 + 1], h2 = vfin[i * 3 + 2];
        float gi[9], gh[9];
        #pragma unroll
        for (int k = 0; k < 9; ++k) gi[k] = u[k] + cnt * c2V[k] + var_bih[k];
        #pragma unroll
        for (int k = 0; k < 9; ++k)
            gh[k] = var_whh[k * 3] * h0 + var_whh[k * 3 + 1] * h1 + var_whh[k * 3 + 2] * h2 + var_bhh[k];
        float r0 = fsig(gi[0] + gh[0]), r1 = fsig(gi[1] + gh[1]), r2 = fsig(gi[2] + gh[2]);
        float z0 = fsig(gi[3] + gh[3]), z1 = fsig(gi[4] + gh[4]), z2 = fsig(gi[5] + gh[5]);
        float n0 = ftanh(gi[6] + r0 * gh[6]);
        float n1 = ftanh(gi[7] + r1 * gh[7]);
        float n2 = ftanh(gi[8] + r2 * gh[8]);
        vfout[i * 3 + 0] = (1.0f - z0) * n0 + z0 * h0;
        vfout[i * 3 + 1] = (1.0f - z1) * n1 + z1 * h1;
        vfout[i * 3 + 2] = (1.0f - z2) * n2 + z2 * h2;
    }
}

extern "C" void kernel_launch(void* const* d_in, const int* in_sizes, int n_in,
                              void* d_out, int out_size, void* d_ws, size_t ws_size,
                              hipStream_t stream) {
    const float* vf0     = (const float*)d_in[0];
    const float* cf0     = (const float*)d_in[1];
    const float* ef      = (const float*)d_in[2];
    const float* v2c_w1  = (const float*)d_in[3];
    const float* v2c_b1  = (const float*)d_in[4];
    const float* v2c_w2  = (const float*)d_in[5];
    const float* v2c_b2  = (const float*)d_in[6];
    const float* c2v_w1  = (const float*)d_in[7];
    const float* c2v_b1  = (const float*)d_in[8];
    const float* c2v_w2  = (const float*)d_in[9];
    const float* c2v_b2  = (const float*)d_in[10];
    const float* var_wih = (const float*)d_in[11];
    const float* var_whh = (const float*)d_in[12];
    const float* var_bih = (const float*)d_in[13];
    const float* var_bhh = (const float*)d_in[14];
    const float* cls_wih = (const float*)d_in[15];
    const float* cls_whh = (const float*)d_in[16];
    const float* cls_bih = (const float*)d_in[17];
    const float* cls_bhh = (const float*)d_in[18];
    const float* att_w1  = (const float*)d_in[19];
    const float* att_b1  = (const float*)d_in[20];
    const float* att_w2  = (const float*)d_in[21];
    const float* att_b2  = (const float*)d_in[22];
    const int*   var_idx = (const int*)d_in[23];
    const int*   cls_idx = (const int*)d_in[24];
    float* dout = (float*)d_out;

    // ---- workspace layout ----
    char* w = (char*)d_ws;
    auto alloc = [&](size_t bytes) { char* p = w; w += (bytes + 255) & ~(size_t)255; return p; };
    int*   rowC   = (int*)alloc((C_N + 1) * 4);
    int*   rowV   = (int*)alloc((V_N + 1) * 4);
    int*   cntC   = (int*)alloc((size_t)C_N * 4);   // cntC/cntV adjacent: single memset
    int*   cntV   = (int*)alloc((size_t)V_N * 4);
    char*  cntEnd = w;
    int*   rankC  = (int*)alloc((size_t)E_N * 4);
    int*   rankV  = (int*)alloc((size_t)E_N * 4);
    int*   bsumC  = (int*)alloc(512 * 4);
    int*   bsumV  = (int*)alloc(512 * 4);
    float* logits = (float*)alloc((size_t)C_N * 4);
    float* pmax   = (float*)alloc(2048 * 4);
    float* Sg     = (float*)alloc(64 * 4);          // per-layer: Sg[2l]=S, Sg[2l+1]=gmax
    float* prep   = (float*)alloc(6 * 1040 * 4);
    int4*  edataC = (int4*)alloc((size_t)E_N * 16);
    int4*  edataV = (int4*)alloc((size_t)E_N * 16);
    float* gsumC  = (float*)alloc((size_t)C_N * 9 * 4);  // gsumC/gsumV adjacent
    float* gsumV  = (float*)alloc((size_t)V_N * 9 * 4);
    char*  gsumEnd = w;
    float* vfW    = (float*)alloc((size_t)V_N * 3 * 4);
    float* cfW    = (float*)alloc((size_t)C_N * 3 * 4);

    const int nbC = (C_N + 1023) / 1024;   // 411
    const int nbV = (V_N + 1023) / 1024;   // 98
    const size_t gsum_bytes = (size_t)gsumEnd - (size_t)gsumC;

    k_prep<<<(6 * 1040 + 255) / 256, 256, 0, stream>>>(
        v2c_w1, v2c_b1, v2c_w2, v2c_b2, c2v_w1, c2v_b1, c2v_w2, c2v_b2,
        cls_wih, var_wih, prep);

    hipMemsetAsync(cntC, 0, (size_t)(cntEnd - (char*)cntC), stream);
    k_countrank<<<NEBLK, 256, 0, stream>>>(cls_idx, var_idx, cntC, cntV, rankC, rankV);
    k_scanA<<<nbC + nbV, 256, 0, stream>>>(cntC, cntV, nbC, bsumC, bsumV);
    k_scanB<<<2, 512, 0, stream>>>(bsumC, nbC, rowC + C_N, bsumV, nbV, rowV + V_N);
    k_scanC<<<nbC + nbV, 256, 0, stream>>>(cntC, cntV, nbC, bsumC, bsumV, rowC, rowV);
    k_permute<<<NEBLK, 256, 0, stream>>>(var_idx, cls_idx, rankC, rankV, ef,
                                         rowC, rowV, edataC, edataV);

    k_att0<<<NCBLK, 256, 0, stream>>>(cf0, att_w1, att_b1, att_w2, att_b2,
                                      logits, pmax, Sg);

    for (int l = 0; l < L_N; ++l) {
        const float* vin = (l == 0) ? vf0 : vfW;
        const float* cin = (l == 0) ? cf0 : cfW;
        float* vout = (l == 2) ? dout : vfW;
        float* cout = (l == 2) ? (dout + (size_t)V_N * 3) : cfW;
        const float* prepA = prep + l * 1040;          // v2c (side 0)
        const float* prepB = prep + (3 + l) * 1040;    // c2v (side 1)
        int la = (l < 2) ? (l + 1) : 2;                // att weights for next layer

        hipMemsetAsync(gsumC, 0, gsum_bytes, stream);

        k_edge2<<<2 * NEBLK, 256, 0, stream>>>(vin, cin, edataC, edataV,
                                               prepA, prepB, logits, pmax,
                                               Sg + 2 * l, gsumC, gsumV);

        k_nodeM<<<NCBLK + NVBLK, 256, 0, stream>>>(gsumC, gsumV, rowC, rowV,
                                                   cin, vin, cout, vout,
                                                   Sg + 2 * l, logits, pmax,
                                                   prepA + 1024, prepB + 1024,
                                                   cls_whh + l * 27, cls_bih + l * 9, cls_bhh + l * 9,
                                                   var_whh + l * 27, var_bih + l * 9, var_bhh + l * 9,
                                                   att_w1 + la * 192, att_b1 + la * 64,
                                                   att_w2 + la * 64, att_b2 + la,
                                                   (l < 2) ? 1 : 0);
    }
}